// Round 4
// baseline (466.868 us; speedup 1.0000x reference)
//
#include <hip/hip_runtime.h>

#define N_NODES 100000
#define N_EDGES 1600000
#define F_IN    128
#define F_OUT   32

#define BKT_SHIFT  7
#define NBKT       782          // ceil(100000/128)
#define BKT_STRIDE 2560         // mean 2046, sigma~45 -> +11 sigma headroom
#define BIN_TILE   4096
#define NTILES     ((N_EDGES + BIN_TILE - 1) / BIN_TILE)   // 391

__global__ void init_kernel(int* __restrict__ deg, int* __restrict__ gcur) {
    int i = blockIdx.x * blockDim.x + threadIdx.x;
    if (i < N_NODES) deg[i] = 0;
    if (i < NBKT)    gcur[i] = 0;
}

__global__ void hist_kernel(const int* __restrict__ ei, int* __restrict__ deg) {
    int e = blockIdx.x * blockDim.x + threadIdx.x;
    if (e < N_EDGES) atomicAdd(&deg[ei[N_EDGES + e]], 1);
}

__global__ void dinv_kernel(const int* __restrict__ deg, float* __restrict__ dinv) {
    int i = blockIdx.x * blockDim.x + threadIdx.x;
    if (i < N_NODES) dinv[i] = rsqrtf((float)(deg[i] + 1));  // +1 self loop
}

// Bin edges by dst>>7 into 782 buckets. Per-block LDS hist + one global cursor
// bump per (tile,bucket) keeps same-bucket writes consecutive -> L2 line merge.
__global__ __launch_bounds__(256) void bin_kernel(const int* __restrict__ ei,
                                                  int* __restrict__ gcur,
                                                  unsigned int* __restrict__ binned) {
    __shared__ int cnt[NBKT], pos[NBKT], gbase[NBKT];
    int t = threadIdx.x;
    for (int b = t; b < NBKT; b += 256) { cnt[b] = 0; pos[b] = 0; }
    __syncthreads();
    int ebase = blockIdx.x * BIN_TILE;
    unsigned int pk[16];
    int bkt[16];
#pragma unroll
    for (int k = 0; k < 16; ++k) {
        int e = ebase + k * 256 + t;
        if (e < N_EDGES) {
            int s = ei[e];
            int d = ei[N_EDGES + e];
            bkt[k] = d >> BKT_SHIFT;
            pk[k]  = (unsigned)s | ((unsigned)(d & 127) << 25);
            atomicAdd(&cnt[bkt[k]], 1);
        } else {
            bkt[k] = -1;
        }
    }
    __syncthreads();
    for (int b = t; b < NBKT; b += 256)
        if (cnt[b] > 0) gbase[b] = atomicAdd(&gcur[b], cnt[b]);
    __syncthreads();
#pragma unroll
    for (int k = 0; k < 16; ++k) {
        if (bkt[k] >= 0) {
            int r = atomicAdd(&pos[bkt[k]], 1);
            int p = gbase[bkt[k]] + r;
            if (p < BKT_STRIDE)
                binned[(size_t)bkt[k] * BKT_STRIDE + p] = pk[k];
        }
    }
}

// h = x @ W. 256 rows/block; K staged transposed in LDS in chunks of 32;
// each thread computes an 8-row x 4-col register tile.
__global__ __launch_bounds__(256) void matmul_kernel(const float4* __restrict__ x4,
                                                     const float4* __restrict__ W4,
                                                     float* __restrict__ h) {
    __shared__ float xsT[32 * 260];       // 33.3 KB, transposed x chunk [k][row]
    __shared__ float Ws[F_IN * F_OUT];    // 16 KB
    int t = threadIdx.x;
#pragma unroll
    for (int k = 0; k < 4; ++k) {
        float4 w = W4[t + k * 256];
        *(float4*)&Ws[(t + k * 256) * 4] = w;
    }
    int rbase = blockIdx.x * 256;
    int rt = t >> 3, ct = t & 7;          // rt: 8-row group, ct: 4-col group
    float accf[32];
#pragma unroll
    for (int i = 0; i < 32; ++i) accf[i] = 0.0f;

    int q = t & 7, rr0 = t >> 3;          // staging mapping: 8 f4/row-slice
    for (int kc = 0; kc < 4; ++kc) {
        __syncthreads();  // previous chunk's compute done before overwrite
#pragma unroll
        for (int it = 0; it < 8; ++it) {
            int r = it * 32 + rr0;
            int grow = rbase + r;
            float4 v = (grow < N_NODES) ? x4[(size_t)grow * 32 + kc * 8 + q]
                                        : make_float4(0, 0, 0, 0);
            xsT[(q * 4 + 0) * 260 + r] = v.x;
            xsT[(q * 4 + 1) * 260 + r] = v.y;
            xsT[(q * 4 + 2) * 260 + r] = v.z;
            xsT[(q * 4 + 3) * 260 + r] = v.w;
        }
        __syncthreads();
#pragma unroll
        for (int k = 0; k < 32; ++k) {
            float4 xa0 = *(const float4*)&xsT[k * 260 + rt * 8];
            float4 xa1 = *(const float4*)&xsT[k * 260 + rt * 8 + 4];
            float4 w   = *(const float4*)&Ws[(kc * 32 + k) * F_OUT + ct * 4];
            float xa[8] = {xa0.x, xa0.y, xa0.z, xa0.w, xa1.x, xa1.y, xa1.z, xa1.w};
            float wv[4] = {w.x, w.y, w.z, w.w};
#pragma unroll
            for (int i = 0; i < 8; ++i)
#pragma unroll
                for (int j = 0; j < 4; ++j)
                    accf[i * 4 + j] += xa[i] * wv[j];
        }
    }
#pragma unroll
    for (int i = 0; i < 8; ++i) {
        int grow = rbase + rt * 8 + i;
        if (grow < N_NODES)
            *(float4*)&h[(size_t)grow * F_OUT + ct * 4] =
                make_float4(accf[i * 4], accf[i * 4 + 1], accf[i * 4 + 2], accf[i * 4 + 3]);
    }
}

// One block per bucket: accumulate Sum h[src]*dinv[src] into a 128x36 LDS tile
// via ds_add_f32, then epilogue applies dinv_dst, self loop, and bias.
__global__ __launch_bounds__(256) void aggregate_kernel(const unsigned int* __restrict__ binned,
                                                        const int* __restrict__ gcur,
                                                        const float* __restrict__ h,
                                                        const float* __restrict__ dinv,
                                                        const float* __restrict__ bias,
                                                        float* __restrict__ out) {
    __shared__ float tile[128 * 36];  // 18 KB, row pad 36 breaks bank aliasing
    int t = threadIdx.x;
    int b = blockIdx.x;
    for (int i = t; i < 128 * 36; i += 256) tile[i] = 0.0f;
    __syncthreads();
    int ne = gcur[b];
    if (ne > BKT_STRIDE) ne = BKT_STRIDE;
    const unsigned int* eb = binned + (size_t)b * BKT_STRIDE;
    int slot = t >> 3, c = t & 7;     // 32 edges/block-iter, 8 lanes per edge
    for (int base = 0; base < ne; base += 32) {
        int eidx = base + slot;
        if (eidx < ne) {
            unsigned pk = eb[eidx];
            int s  = (int)(pk & 0x1FFFFFF);
            int dl = (int)(pk >> 25);
            float dvs = dinv[s];
            float4 hv = *(const float4*)&h[(size_t)s * F_OUT + c * 4];
            float* tr = &tile[dl * 36 + c * 4];
            atomicAdd(&tr[0], hv.x * dvs);
            atomicAdd(&tr[1], hv.y * dvs);
            atomicAdd(&tr[2], hv.z * dvs);
            atomicAdd(&tr[3], hv.w * dvs);
        }
    }
    __syncthreads();
    int n = t >> 1, ch = (t & 1) * 16;   // 2 threads per node, 16 cols each
    int gnode = b * 128 + n;
    if (gnode < N_NODES) {
        float dv = dinv[gnode];
#pragma unroll
        for (int qq = 0; qq < 4; ++qq) {
            int cc = ch + qq * 4;
            float4 tv = *(const float4*)&tile[n * 36 + cc];
            float4 hv = *(const float4*)&h[(size_t)gnode * F_OUT + cc];
            float4 bv = *(const float4*)&bias[cc];
            float4 o;
            o.x = bv.x + dv * (tv.x + hv.x * dv);
            o.y = bv.y + dv * (tv.y + hv.y * dv);
            o.z = bv.z + dv * (tv.z + hv.z * dv);
            o.w = bv.w + dv * (tv.w + hv.w * dv);
            *(float4*)&out[(size_t)gnode * F_OUT + cc] = o;
        }
    }
}

extern "C" void kernel_launch(void* const* d_in, const int* in_sizes, int n_in,
                              void* d_out, int out_size, void* d_ws, size_t ws_size,
                              hipStream_t stream) {
    const float* x  = (const float*)d_in[0];
    const int*   ei = (const int*)d_in[1];   // int32 on device
    const float* W  = (const float*)d_in[2];
    const float* b  = (const float*)d_in[3];
    float* out = (float*)d_out;

    int*          deg    = (int*)d_ws;                       // 100000
    float*        dinv   = (float*)(deg + N_NODES);          // 100000
    int*          gcur   = (int*)(dinv + N_NODES);           // NBKT (pad to 1024)
    unsigned int* binned = (unsigned int*)(gcur + 1024);     // NBKT*BKT_STRIDE ~ 8.0 MB
    float*        h      = (float*)(binned + (size_t)NBKT * BKT_STRIDE);  // 12.8 MB

    const int B = 256;
    const int gN = (N_NODES + B - 1) / B;   // 391
    const int gE = (N_EDGES + B - 1) / B;   // 6250

    init_kernel<<<gN, B, 0, stream>>>(deg, gcur);
    hist_kernel<<<gE, B, 0, stream>>>(ei, deg);
    dinv_kernel<<<gN, B, 0, stream>>>(deg, dinv);

    bin_kernel<<<NTILES, B, 0, stream>>>(ei, gcur, binned);

    matmul_kernel<<<gN, B, 0, stream>>>((const float4*)x, (const float4*)W, h);

    aggregate_kernel<<<NBKT, B, 0, stream>>>(binned, gcur, h, dinv, b, out);
}

// Round 5
// 183.650 us; speedup vs baseline: 2.5422x; 2.5422x over previous
//
#include <hip/hip_runtime.h>

#define N_NODES 100000
#define N_EDGES 1600000
#define F_IN    128
#define F_OUT   32

#define BKT_SHIFT  7
#define BKT_SIZE   128
#define NBKT       782          // ceil(100000/128)
#define BKT_STRIDE 2560         // mean 2046 per bucket, +11 sigma headroom
#define BIN_TILE   4096
#define NTILES     ((N_EDGES + BIN_TILE - 1) / BIN_TILE)   // 391

__global__ void init_kernel(int* __restrict__ deg, int* __restrict__ gcur) {
    int i = blockIdx.x * blockDim.x + threadIdx.x;
    if (i < N_NODES) deg[i] = 0;
    if (i < NBKT)    gcur[i] = 0;
}

__global__ void hist_kernel(const int* __restrict__ ei, int* __restrict__ deg) {
    int e = blockIdx.x * blockDim.x + threadIdx.x;
    if (e < N_EDGES) atomicAdd(&deg[ei[N_EDGES + e]], 1);
}

__global__ void dinv_kernel(const int* __restrict__ deg, float* __restrict__ dinv) {
    int i = blockIdx.x * blockDim.x + threadIdx.x;
    if (i < N_NODES) dinv[i] = rsqrtf((float)(deg[i] + 1));  // +1 self loop
}

// Bin edges by dst>>7 into 782 buckets; per-(tile,bucket) runs are consecutive
// in the bucket so the random line-dirtying of a full sort is avoided.
__global__ __launch_bounds__(256) void bin_kernel(const int* __restrict__ ei,
                                                  int* __restrict__ gcur,
                                                  unsigned int* __restrict__ binned) {
    __shared__ int cnt[NBKT], pos[NBKT], gbase[NBKT];
    int t = threadIdx.x;
    for (int b = t; b < NBKT; b += 256) { cnt[b] = 0; pos[b] = 0; }
    __syncthreads();
    int ebase = blockIdx.x * BIN_TILE;
    unsigned int pk[16];
    int bkt[16];
#pragma unroll
    for (int k = 0; k < 16; ++k) {
        int e = ebase + k * 256 + t;
        if (e < N_EDGES) {
            int s = ei[e];
            int d = ei[N_EDGES + e];
            bkt[k] = d >> BKT_SHIFT;
            pk[k]  = (unsigned)s | ((unsigned)(d & (BKT_SIZE - 1)) << 25);
            atomicAdd(&cnt[bkt[k]], 1);
        } else {
            bkt[k] = -1;
        }
    }
    __syncthreads();
    for (int b = t; b < NBKT; b += 256)
        if (cnt[b] > 0) gbase[b] = atomicAdd(&gcur[b], cnt[b]);
    __syncthreads();
#pragma unroll
    for (int k = 0; k < 16; ++k) {
        if (bkt[k] >= 0) {
            int r = atomicAdd(&pos[bkt[k]], 1);
            int p = gbase[bkt[k]] + r;
            if (p < BKT_STRIDE)
                binned[(size_t)bkt[k] * BKT_STRIDE + p] = pk[k];
        }
    }
}

// hs = (x @ W) * dinv[row]  (dinv folded in so the edge phase needs no dinv gather)
__global__ __launch_bounds__(256) void matmul_kernel(const float4* __restrict__ x4,
                                                     const float4* __restrict__ W4,
                                                     const float* __restrict__ dinv,
                                                     float* __restrict__ hs) {
    __shared__ float xsT[32 * 260];       // transposed x chunk [k][row]
    __shared__ float Ws[F_IN * F_OUT];
    int t = threadIdx.x;
#pragma unroll
    for (int k = 0; k < 4; ++k) {
        float4 w = W4[t + k * 256];
        *(float4*)&Ws[(t + k * 256) * 4] = w;
    }
    int rbase = blockIdx.x * 256;
    int rt = t >> 3, ct = t & 7;
    float accf[32];
#pragma unroll
    for (int i = 0; i < 32; ++i) accf[i] = 0.0f;

    int q = t & 7, rr0 = t >> 3;
    for (int kc = 0; kc < 4; ++kc) {
        __syncthreads();
#pragma unroll
        for (int it = 0; it < 8; ++it) {
            int r = it * 32 + rr0;
            int grow = rbase + r;
            float4 v = (grow < N_NODES) ? x4[(size_t)grow * 32 + kc * 8 + q]
                                        : make_float4(0, 0, 0, 0);
            xsT[(q * 4 + 0) * 260 + r] = v.x;
            xsT[(q * 4 + 1) * 260 + r] = v.y;
            xsT[(q * 4 + 2) * 260 + r] = v.z;
            xsT[(q * 4 + 3) * 260 + r] = v.w;
        }
        __syncthreads();
#pragma unroll
        for (int k = 0; k < 32; ++k) {
            float4 xa0 = *(const float4*)&xsT[k * 260 + rt * 8];
            float4 xa1 = *(const float4*)&xsT[k * 260 + rt * 8 + 4];
            float4 w   = *(const float4*)&Ws[(kc * 32 + k) * F_OUT + ct * 4];
            float xa[8] = {xa0.x, xa0.y, xa0.z, xa0.w, xa1.x, xa1.y, xa1.z, xa1.w};
            float wv[4] = {w.x, w.y, w.z, w.w};
#pragma unroll
            for (int i = 0; i < 8; ++i)
#pragma unroll
                for (int j = 0; j < 4; ++j)
                    accf[i * 4 + j] += xa[i] * wv[j];
        }
    }
#pragma unroll
    for (int i = 0; i < 8; ++i) {
        int grow = rbase + rt * 8 + i;
        if (grow < N_NODES) {
            float dv = dinv[grow];
            *(float4*)&hs[(size_t)grow * F_OUT + ct * 4] =
                make_float4(accf[i * 4] * dv, accf[i * 4 + 1] * dv,
                            accf[i * 4 + 2] * dv, accf[i * 4 + 3] * dv);
        }
    }
}

// One block per bucket: in-LDS counting sort by dst_local (int atomics only),
// then per-node register accumulation over its contiguous sources.
__global__ __launch_bounds__(256) void aggregate_kernel(const unsigned int* __restrict__ binned,
                                                        const int* __restrict__ gcur,
                                                        const float* __restrict__ hs,
                                                        const float* __restrict__ dinv,
                                                        const float* __restrict__ bias,
                                                        float* __restrict__ out) {
    __shared__ int scan[BKT_SIZE];
    __shared__ int rp[BKT_SIZE + 1];
    __shared__ int cur[BKT_SIZE];
    __shared__ int se[BKT_STRIDE];       // sorted src ids, 10 KB
    int t = threadIdx.x;
    int b = blockIdx.x;
    int ne = gcur[b];
    if (ne > BKT_STRIDE) ne = BKT_STRIDE;
    const unsigned int* eb = binned + (size_t)b * BKT_STRIDE;

    if (t < BKT_SIZE) scan[t] = 0;
    __syncthreads();
    for (int i = t; i < ne; i += 256)
        atomicAdd(&scan[eb[i] >> 25], 1);
    __syncthreads();
    int v = (t < BKT_SIZE) ? scan[t] : 0;
    // Hillis-Steele inclusive scan over 128 entries (barriers block-uniform)
    for (int off = 1; off < BKT_SIZE; off <<= 1) {
        int add = (t < BKT_SIZE && t >= off) ? scan[t - off] : 0;
        __syncthreads();
        if (t < BKT_SIZE) scan[t] += add;
        __syncthreads();
    }
    if (t < BKT_SIZE) {
        int ex = scan[t] - v;            // exclusive prefix
        rp[t] = ex;
        cur[t] = ex;
    }
    if (t == 0) rp[BKT_SIZE] = ne;
    __syncthreads();
    for (int i = t; i < ne; i += 256) {
        unsigned pk = eb[i];
        int dl = (int)(pk >> 25);
        int r = atomicAdd(&cur[dl], 1);
        se[r] = (int)(pk & 0x1FFFFFF);
    }
    __syncthreads();

    int g = t >> 5, j = t & 31;          // 8 node-groups x 32 column lanes
    for (int n = g; n < BKT_SIZE; n += 8) {
        int gnode = b * BKT_SIZE + n;
        if (gnode >= N_NODES) break;
        int beg = rp[n], end = rp[n + 1];
        float acc = 0.0f;
        int p = beg;
        for (; p + 3 < end; p += 4) {    // 4 independent gathers in flight
            int s0 = se[p], s1 = se[p + 1], s2 = se[p + 2], s3 = se[p + 3];
            float a0 = hs[(size_t)s0 * F_OUT + j];
            float a1 = hs[(size_t)s1 * F_OUT + j];
            float a2 = hs[(size_t)s2 * F_OUT + j];
            float a3 = hs[(size_t)s3 * F_OUT + j];
            acc += a0 + a1 + a2 + a3;
        }
        for (; p < end; ++p)
            acc += hs[(size_t)se[p] * F_OUT + j];
        float dv = dinv[gnode];
        float self = hs[(size_t)gnode * F_OUT + j];
        out[(size_t)gnode * F_OUT + j] = bias[j] + dv * (acc + self);
    }
}

extern "C" void kernel_launch(void* const* d_in, const int* in_sizes, int n_in,
                              void* d_out, int out_size, void* d_ws, size_t ws_size,
                              hipStream_t stream) {
    const float* x  = (const float*)d_in[0];
    const int*   ei = (const int*)d_in[1];   // int32 on device
    const float* W  = (const float*)d_in[2];
    const float* b  = (const float*)d_in[3];
    float* out = (float*)d_out;

    int*          deg    = (int*)d_ws;                       // 100000
    float*        dinv   = (float*)(deg + N_NODES);          // 100000
    int*          gcur   = (int*)(dinv + N_NODES);           // pad to 1024
    unsigned int* binned = (unsigned int*)(gcur + 1024);     // NBKT*BKT_STRIDE ~8 MB
    float*        hs     = (float*)(binned + (size_t)NBKT * BKT_STRIDE);  // 12.8 MB

    const int B = 256;
    const int gN = (N_NODES + B - 1) / B;   // 391
    const int gE = (N_EDGES + B - 1) / B;   // 6250

    init_kernel<<<gN, B, 0, stream>>>(deg, gcur);
    hist_kernel<<<gE, B, 0, stream>>>(ei, deg);
    dinv_kernel<<<gN, B, 0, stream>>>(deg, dinv);

    bin_kernel<<<NTILES, B, 0, stream>>>(ei, gcur, binned);

    matmul_kernel<<<gN, B, 0, stream>>>((const float4*)x, (const float4*)W, dinv, hs);

    aggregate_kernel<<<NBKT, B, 0, stream>>>(binned, gcur, hs, dinv, b, out);
}

// Round 6
// 118.470 us; speedup vs baseline: 3.9408x; 1.5502x over previous
//
#include <hip/hip_runtime.h>

#define N_NODES 100000
#define N_EDGES 1600000
#define F_IN    128
#define F_OUT   32

#define BKT_SHIFT  7
#define BKT_SIZE   128
#define NBKT       782          // ceil(100000/128)
#define BKT_STRIDE 2560         // mean 2046 per bucket, +11 sigma headroom
#define BIN_TILE   4096
#define NTILES     ((N_EDGES + BIN_TILE - 1) / BIN_TILE)   // 391

__global__ void init_kernel(int* __restrict__ gcur) {
    int i = blockIdx.x * blockDim.x + threadIdx.x;
    if (i < NBKT) gcur[i] = 0;
}

// Bin edges by dst>>7 into 782 buckets; per-(tile,bucket) runs are consecutive
// in the bucket so the random line-dirtying of a full sort is avoided.
__global__ __launch_bounds__(256) void bin_kernel(const int* __restrict__ ei,
                                                  int* __restrict__ gcur,
                                                  unsigned int* __restrict__ binned) {
    __shared__ int cnt[NBKT], pos[NBKT], gbase[NBKT];
    int t = threadIdx.x;
    for (int b = t; b < NBKT; b += 256) { cnt[b] = 0; pos[b] = 0; }
    __syncthreads();
    int ebase = blockIdx.x * BIN_TILE;
    unsigned int pk[16];
    int bkt[16];
#pragma unroll
    for (int k = 0; k < 16; ++k) {
        int e = ebase + k * 256 + t;
        if (e < N_EDGES) {
            int s = ei[e];
            int d = ei[N_EDGES + e];
            bkt[k] = d >> BKT_SHIFT;
            pk[k]  = (unsigned)s | ((unsigned)(d & (BKT_SIZE - 1)) << 25);
            atomicAdd(&cnt[bkt[k]], 1);
        } else {
            bkt[k] = -1;
        }
    }
    __syncthreads();
    for (int b = t; b < NBKT; b += 256)
        if (cnt[b] > 0) gbase[b] = atomicAdd(&gcur[b], cnt[b]);
    __syncthreads();
#pragma unroll
    for (int k = 0; k < 16; ++k) {
        if (bkt[k] >= 0) {
            int r = atomicAdd(&pos[bkt[k]], 1);
            int p = gbase[bkt[k]] + r;
            if (p < BKT_STRIDE)
                binned[(size_t)bkt[k] * BKT_STRIDE + p] = pk[k];
        }
    }
}

// Degrees come straight from the binned edges: 128-entry LDS histogram per
// bucket (native int ds_add), then dinv = rsqrt(count + 1 self-loop).
__global__ __launch_bounds__(256) void dinv_from_bins_kernel(const unsigned int* __restrict__ binned,
                                                             const int* __restrict__ gcur,
                                                             float* __restrict__ dinv) {
    __shared__ int cnt[BKT_SIZE];
    int t = threadIdx.x;
    int b = blockIdx.x;
    if (t < BKT_SIZE) cnt[t] = 0;
    __syncthreads();
    int ne = gcur[b];
    if (ne > BKT_STRIDE) ne = BKT_STRIDE;
    const unsigned int* eb = binned + (size_t)b * BKT_STRIDE;
    for (int i = t; i < ne; i += 256)
        atomicAdd(&cnt[eb[i] >> 25], 1);
    __syncthreads();
    int gnode = b * BKT_SIZE + t;
    if (t < BKT_SIZE && gnode < N_NODES)
        dinv[gnode] = rsqrtf((float)(cnt[t] + 1));
}

// hs = (x @ W) * dinv[row]  (dinv folded in so the edge phase needs no dinv gather)
__global__ __launch_bounds__(256) void matmul_kernel(const float4* __restrict__ x4,
                                                     const float4* __restrict__ W4,
                                                     const float* __restrict__ dinv,
                                                     float* __restrict__ hs) {
    __shared__ float xsT[32 * 260];       // transposed x chunk [k][row]
    __shared__ float Ws[F_IN * F_OUT];
    int t = threadIdx.x;
#pragma unroll
    for (int k = 0; k < 4; ++k) {
        float4 w = W4[t + k * 256];
        *(float4*)&Ws[(t + k * 256) * 4] = w;
    }
    int rbase = blockIdx.x * 256;
    int rt = t >> 3, ct = t & 7;
    float accf[32];
#pragma unroll
    for (int i = 0; i < 32; ++i) accf[i] = 0.0f;

    int q = t & 7, rr0 = t >> 3;
    for (int kc = 0; kc < 4; ++kc) {
        __syncthreads();
#pragma unroll
        for (int it = 0; it < 8; ++it) {
            int r = it * 32 + rr0;
            int grow = rbase + r;
            float4 v = (grow < N_NODES) ? x4[(size_t)grow * 32 + kc * 8 + q]
                                        : make_float4(0, 0, 0, 0);
            xsT[(q * 4 + 0) * 260 + r] = v.x;
            xsT[(q * 4 + 1) * 260 + r] = v.y;
            xsT[(q * 4 + 2) * 260 + r] = v.z;
            xsT[(q * 4 + 3) * 260 + r] = v.w;
        }
        __syncthreads();
#pragma unroll
        for (int k = 0; k < 32; ++k) {
            float4 xa0 = *(const float4*)&xsT[k * 260 + rt * 8];
            float4 xa1 = *(const float4*)&xsT[k * 260 + rt * 8 + 4];
            float4 w   = *(const float4*)&Ws[(kc * 32 + k) * F_OUT + ct * 4];
            float xa[8] = {xa0.x, xa0.y, xa0.z, xa0.w, xa1.x, xa1.y, xa1.z, xa1.w};
            float wv[4] = {w.x, w.y, w.z, w.w};
#pragma unroll
            for (int i = 0; i < 8; ++i)
#pragma unroll
                for (int j = 0; j < 4; ++j)
                    accf[i * 4 + j] += xa[i] * wv[j];
        }
    }
#pragma unroll
    for (int i = 0; i < 8; ++i) {
        int grow = rbase + rt * 8 + i;
        if (grow < N_NODES) {
            float dv = dinv[grow];
            *(float4*)&hs[(size_t)grow * F_OUT + ct * 4] =
                make_float4(accf[i * 4] * dv, accf[i * 4 + 1] * dv,
                            accf[i * 4 + 2] * dv, accf[i * 4 + 3] * dv);
        }
    }
}

// One block per bucket: in-LDS counting sort by dst_local (int atomics only),
// then per-node register accumulation over its contiguous sources.
__global__ __launch_bounds__(256) void aggregate_kernel(const unsigned int* __restrict__ binned,
                                                        const int* __restrict__ gcur,
                                                        const float* __restrict__ hs,
                                                        const float* __restrict__ dinv,
                                                        const float* __restrict__ bias,
                                                        float* __restrict__ out) {
    __shared__ int scan[BKT_SIZE];
    __shared__ int rp[BKT_SIZE + 1];
    __shared__ int cur[BKT_SIZE];
    __shared__ int se[BKT_STRIDE];       // sorted src ids, 10 KB
    int t = threadIdx.x;
    int b = blockIdx.x;
    int ne = gcur[b];
    if (ne > BKT_STRIDE) ne = BKT_STRIDE;
    const unsigned int* eb = binned + (size_t)b * BKT_STRIDE;

    if (t < BKT_SIZE) scan[t] = 0;
    __syncthreads();
    for (int i = t; i < ne; i += 256)
        atomicAdd(&scan[eb[i] >> 25], 1);
    __syncthreads();
    int v = (t < BKT_SIZE) ? scan[t] : 0;
    // Hillis-Steele inclusive scan over 128 entries (barriers block-uniform)
    for (int off = 1; off < BKT_SIZE; off <<= 1) {
        int add = (t < BKT_SIZE && t >= off) ? scan[t - off] : 0;
        __syncthreads();
        if (t < BKT_SIZE) scan[t] += add;
        __syncthreads();
    }
    if (t < BKT_SIZE) {
        int ex = scan[t] - v;            // exclusive prefix
        rp[t] = ex;
        cur[t] = ex;
    }
    if (t == 0) rp[BKT_SIZE] = ne;
    __syncthreads();
    for (int i = t; i < ne; i += 256) {
        unsigned pk = eb[i];
        int dl = (int)(pk >> 25);
        int r = atomicAdd(&cur[dl], 1);
        se[r] = (int)(pk & 0x1FFFFFF);
    }
    __syncthreads();

    int g = t >> 5, j = t & 31;          // 8 node-groups x 32 column lanes
    for (int n = g; n < BKT_SIZE; n += 8) {
        int gnode = b * BKT_SIZE + n;
        if (gnode >= N_NODES) break;
        int beg = rp[n], end = rp[n + 1];
        float acc = 0.0f;
        int p = beg;
        for (; p + 3 < end; p += 4) {    // 4 independent gathers in flight
            int s0 = se[p], s1 = se[p + 1], s2 = se[p + 2], s3 = se[p + 3];
            float a0 = hs[(size_t)s0 * F_OUT + j];
            float a1 = hs[(size_t)s1 * F_OUT + j];
            float a2 = hs[(size_t)s2 * F_OUT + j];
            float a3 = hs[(size_t)s3 * F_OUT + j];
            acc += a0 + a1 + a2 + a3;
        }
        for (; p < end; ++p)
            acc += hs[(size_t)se[p] * F_OUT + j];
        float dv = dinv[gnode];
        float self = hs[(size_t)gnode * F_OUT + j];
        out[(size_t)gnode * F_OUT + j] = bias[j] + dv * (acc + self);
    }
}

extern "C" void kernel_launch(void* const* d_in, const int* in_sizes, int n_in,
                              void* d_out, int out_size, void* d_ws, size_t ws_size,
                              hipStream_t stream) {
    const float* x  = (const float*)d_in[0];
    const int*   ei = (const int*)d_in[1];   // int32 on device
    const float* W  = (const float*)d_in[2];
    const float* b  = (const float*)d_in[3];
    float* out = (float*)d_out;

    int*          gcur   = (int*)d_ws;                       // pad to 1024
    unsigned int* binned = (unsigned int*)(gcur + 1024);     // NBKT*BKT_STRIDE ~8 MB
    float*        dinv   = (float*)(binned + (size_t)NBKT * BKT_STRIDE);  // 100000
    float*        hs     = dinv + ((N_NODES + 3) & ~3);      // 12.8 MB

    const int B = 256;
    const int gN = (N_NODES + B - 1) / B;   // 391

    init_kernel<<<1, 1024, 0, stream>>>(gcur);

    bin_kernel<<<NTILES, B, 0, stream>>>(ei, gcur, binned);

    dinv_from_bins_kernel<<<NBKT, B, 0, stream>>>(binned, gcur, dinv);

    matmul_kernel<<<gN, B, 0, stream>>>((const float4*)x, (const float4*)W, dinv, hs);

    aggregate_kernel<<<NBKT, B, 0, stream>>>(binned, gcur, hs, dinv, b, out);
}

// Round 7
// 94.724 us; speedup vs baseline: 4.9287x; 1.2507x over previous
//
#include <hip/hip_runtime.h>
#include <hip/hip_fp16.h>

#define N_NODES 100000
#define N_EDGES 1600000
#define F_IN    128
#define F_OUT   32

#define BKT_SHIFT  7
#define BKT_SIZE   128
#define NBKT       782          // ceil(100000/128)
#define BKT_STRIDE 2560         // mean 2046 per bucket, +11 sigma headroom
#define BIN_TILE   8192
#define EPT        32           // edges per thread in bin_kernel
#define NTILES     ((N_EDGES + BIN_TILE - 1) / BIN_TILE)   // 196

__global__ void init_kernel(int* __restrict__ gcur) {
    int i = blockIdx.x * blockDim.x + threadIdx.x;
    if (i < NBKT) gcur[i] = 0;
}

// Bin edges by dst>>7 into 782 buckets; per-(tile,bucket) runs are consecutive
// in the bucket so same-bucket writes share cache lines.
__global__ __launch_bounds__(256) void bin_kernel(const int* __restrict__ ei,
                                                  int* __restrict__ gcur,
                                                  unsigned int* __restrict__ binned) {
    __shared__ int cnt[NBKT], pos[NBKT], gbase[NBKT];
    int t = threadIdx.x;
    for (int b = t; b < NBKT; b += 256) { cnt[b] = 0; pos[b] = 0; }
    __syncthreads();
    int ebase = blockIdx.x * BIN_TILE;
    unsigned int pk[EPT];
    short bkt[EPT];
#pragma unroll
    for (int k = 0; k < EPT; ++k) {
        int e = ebase + k * 256 + t;
        if (e < N_EDGES) {
            int s = ei[e];
            int d = ei[N_EDGES + e];
            bkt[k] = (short)(d >> BKT_SHIFT);
            pk[k]  = (unsigned)s | ((unsigned)(d & (BKT_SIZE - 1)) << 25);
            atomicAdd(&cnt[bkt[k]], 1);
        } else {
            bkt[k] = -1;
        }
    }
    __syncthreads();
    for (int b = t; b < NBKT; b += 256)
        if (cnt[b] > 0) gbase[b] = atomicAdd(&gcur[b], cnt[b]);
    __syncthreads();
#pragma unroll
    for (int k = 0; k < EPT; ++k) {
        if (bkt[k] >= 0) {
            int r = atomicAdd(&pos[bkt[k]], 1);
            int p = gbase[bkt[k]] + r;
            if (p < BKT_STRIDE)
                binned[(size_t)bkt[k] * BKT_STRIDE + p] = pk[k];
        }
    }
}

// Degrees from binned edges: 128-entry LDS int histogram per bucket.
__global__ __launch_bounds__(256) void dinv_from_bins_kernel(const unsigned int* __restrict__ binned,
                                                             const int* __restrict__ gcur,
                                                             float* __restrict__ dinv) {
    __shared__ int cnt[BKT_SIZE];
    int t = threadIdx.x;
    int b = blockIdx.x;
    if (t < BKT_SIZE) cnt[t] = 0;
    __syncthreads();
    int ne = gcur[b];
    if (ne > BKT_STRIDE) ne = BKT_STRIDE;
    const unsigned int* eb = binned + (size_t)b * BKT_STRIDE;
    for (int i = t; i < ne; i += 256)
        atomicAdd(&cnt[eb[i] >> 25], 1);
    __syncthreads();
    int gnode = b * BKT_SIZE + t;
    if (t < BKT_SIZE && gnode < N_NODES)
        dinv[gnode] = rsqrtf((float)(cnt[t] + 1));
}

// hs = fp16( (x @ W) * dinv[row] )
__global__ __launch_bounds__(256) void matmul_kernel(const float4* __restrict__ x4,
                                                     const float4* __restrict__ W4,
                                                     const float* __restrict__ dinv,
                                                     __half* __restrict__ hs) {
    __shared__ float xsT[32 * 260];       // transposed x chunk [k][row]
    __shared__ float Ws[F_IN * F_OUT];
    int t = threadIdx.x;
#pragma unroll
    for (int k = 0; k < 4; ++k) {
        float4 w = W4[t + k * 256];
        *(float4*)&Ws[(t + k * 256) * 4] = w;
    }
    int rbase = blockIdx.x * 256;
    int rt = t >> 3, ct = t & 7;
    float accf[32];
#pragma unroll
    for (int i = 0; i < 32; ++i) accf[i] = 0.0f;

    int q = t & 7, rr0 = t >> 3;
    for (int kc = 0; kc < 4; ++kc) {
        __syncthreads();
#pragma unroll
        for (int it = 0; it < 8; ++it) {
            int r = it * 32 + rr0;
            int grow = rbase + r;
            float4 v = (grow < N_NODES) ? x4[(size_t)grow * 32 + kc * 8 + q]
                                        : make_float4(0, 0, 0, 0);
            xsT[(q * 4 + 0) * 260 + r] = v.x;
            xsT[(q * 4 + 1) * 260 + r] = v.y;
            xsT[(q * 4 + 2) * 260 + r] = v.z;
            xsT[(q * 4 + 3) * 260 + r] = v.w;
        }
        __syncthreads();
#pragma unroll
        for (int k = 0; k < 32; ++k) {
            float4 xa0 = *(const float4*)&xsT[k * 260 + rt * 8];
            float4 xa1 = *(const float4*)&xsT[k * 260 + rt * 8 + 4];
            float4 w   = *(const float4*)&Ws[(kc * 32 + k) * F_OUT + ct * 4];
            float xa[8] = {xa0.x, xa0.y, xa0.z, xa0.w, xa1.x, xa1.y, xa1.z, xa1.w};
            float wv[4] = {w.x, w.y, w.z, w.w};
#pragma unroll
            for (int i = 0; i < 8; ++i)
#pragma unroll
                for (int j = 0; j < 4; ++j)
                    accf[i * 4 + j] += xa[i] * wv[j];
        }
    }
#pragma unroll
    for (int i = 0; i < 8; ++i) {
        int grow = rbase + rt * 8 + i;
        if (grow < N_NODES) {
            float dv = dinv[grow];
            __half2 p0 = __floats2half2_rn(accf[i * 4] * dv, accf[i * 4 + 1] * dv);
            __half2 p1 = __floats2half2_rn(accf[i * 4 + 2] * dv, accf[i * 4 + 3] * dv);
            __half2* dst = (__half2*)&hs[(size_t)grow * F_OUT + ct * 4];
            dst[0] = p0;
            dst[1] = p1;
        }
    }
}

// One block per bucket: in-LDS counting sort by dst_local (int atomics only),
// then per-node register accumulation: 16 lanes per node, half2 gathers.
__global__ __launch_bounds__(256) void aggregate_kernel(const unsigned int* __restrict__ binned,
                                                        const int* __restrict__ gcur,
                                                        const __half2* __restrict__ hs2,
                                                        const float* __restrict__ dinv,
                                                        const float* __restrict__ bias,
                                                        float* __restrict__ out) {
    __shared__ int scan[BKT_SIZE];
    __shared__ int rp[BKT_SIZE + 1];
    __shared__ int cur[BKT_SIZE];
    __shared__ int se[BKT_STRIDE];       // sorted src ids, 10 KB
    int t = threadIdx.x;
    int b = blockIdx.x;
    int ne = gcur[b];
    if (ne > BKT_STRIDE) ne = BKT_STRIDE;
    const unsigned int* eb = binned + (size_t)b * BKT_STRIDE;

    if (t < BKT_SIZE) scan[t] = 0;
    __syncthreads();
    for (int i = t; i < ne; i += 256)
        atomicAdd(&scan[eb[i] >> 25], 1);
    __syncthreads();
    int v = (t < BKT_SIZE) ? scan[t] : 0;
    for (int off = 1; off < BKT_SIZE; off <<= 1) {
        int add = (t < BKT_SIZE && t >= off) ? scan[t - off] : 0;
        __syncthreads();
        if (t < BKT_SIZE) scan[t] += add;
        __syncthreads();
    }
    if (t < BKT_SIZE) {
        int ex = scan[t] - v;            // exclusive prefix
        rp[t] = ex;
        cur[t] = ex;
    }
    if (t == 0) rp[BKT_SIZE] = ne;
    __syncthreads();
    for (int i = t; i < ne; i += 256) {
        unsigned pk = eb[i];
        int dl = (int)(pk >> 25);
        int r = atomicAdd(&cur[dl], 1);
        se[r] = (int)(pk & 0x1FFFFFF);
    }
    __syncthreads();

    int g = t >> 4, j2 = t & 15;         // 16 node-groups x 16 lanes (2 cols/lane)
    for (int n = g; n < BKT_SIZE; n += 16) {
        int gnode = b * BKT_SIZE + n;
        if (gnode >= N_NODES) break;
        int beg = rp[n], end = rp[n + 1];
        float ax = 0.0f, ay = 0.0f;
        int p = beg;
        for (; p + 7 < end; p += 8) {    // 8 independent 4B gathers in flight
            float2 f0 = __half22float2(hs2[(size_t)se[p]     * 16 + j2]);
            float2 f1 = __half22float2(hs2[(size_t)se[p + 1] * 16 + j2]);
            float2 f2 = __half22float2(hs2[(size_t)se[p + 2] * 16 + j2]);
            float2 f3 = __half22float2(hs2[(size_t)se[p + 3] * 16 + j2]);
            float2 f4 = __half22float2(hs2[(size_t)se[p + 4] * 16 + j2]);
            float2 f5 = __half22float2(hs2[(size_t)se[p + 5] * 16 + j2]);
            float2 f6 = __half22float2(hs2[(size_t)se[p + 6] * 16 + j2]);
            float2 f7 = __half22float2(hs2[(size_t)se[p + 7] * 16 + j2]);
            ax += ((f0.x + f1.x) + (f2.x + f3.x)) + ((f4.x + f5.x) + (f6.x + f7.x));
            ay += ((f0.y + f1.y) + (f2.y + f3.y)) + ((f4.y + f5.y) + (f6.y + f7.y));
        }
        for (; p + 3 < end; p += 4) {
            float2 f0 = __half22float2(hs2[(size_t)se[p]     * 16 + j2]);
            float2 f1 = __half22float2(hs2[(size_t)se[p + 1] * 16 + j2]);
            float2 f2 = __half22float2(hs2[(size_t)se[p + 2] * 16 + j2]);
            float2 f3 = __half22float2(hs2[(size_t)se[p + 3] * 16 + j2]);
            ax += (f0.x + f1.x) + (f2.x + f3.x);
            ay += (f0.y + f1.y) + (f2.y + f3.y);
        }
        for (; p < end; ++p) {
            float2 f0 = __half22float2(hs2[(size_t)se[p] * 16 + j2]);
            ax += f0.x;
            ay += f0.y;
        }
        float dv = dinv[gnode];
        float2 sf = __half22float2(hs2[(size_t)gnode * 16 + j2]);
        float2 o;
        o.x = bias[2 * j2]     + dv * (ax + sf.x);
        o.y = bias[2 * j2 + 1] + dv * (ay + sf.y);
        *(float2*)&out[(size_t)gnode * F_OUT + 2 * j2] = o;
    }
}

extern "C" void kernel_launch(void* const* d_in, const int* in_sizes, int n_in,
                              void* d_out, int out_size, void* d_ws, size_t ws_size,
                              hipStream_t stream) {
    const float* x  = (const float*)d_in[0];
    const int*   ei = (const int*)d_in[1];   // int32 on device
    const float* W  = (const float*)d_in[2];
    const float* b  = (const float*)d_in[3];
    float* out = (float*)d_out;

    int*          gcur   = (int*)d_ws;                       // pad to 1024
    unsigned int* binned = (unsigned int*)(gcur + 1024);     // NBKT*BKT_STRIDE ~8 MB
    float*        dinv   = (float*)(binned + (size_t)NBKT * BKT_STRIDE);  // 100000
    __half*       hs     = (__half*)(dinv + ((N_NODES + 3) & ~3));        // 6.4 MB

    const int B = 256;
    const int gN = (N_NODES + B - 1) / B;   // 391

    init_kernel<<<1, 1024, 0, stream>>>(gcur);

    bin_kernel<<<NTILES, B, 0, stream>>>(ei, gcur, binned);

    dinv_from_bins_kernel<<<NBKT, B, 0, stream>>>(binned, gcur, dinv);

    matmul_kernel<<<gN, B, 0, stream>>>((const float4*)x, (const float4*)W, dinv, hs);

    aggregate_kernel<<<NBKT, B, 0, stream>>>(binned, gcur, (const __half2*)hs, dinv, b, out);
}

// Round 8
// 92.346 us; speedup vs baseline: 5.0556x; 1.0257x over previous
//
#include <hip/hip_runtime.h>
#include <hip/hip_fp16.h>

#define N_NODES 100000
#define N_EDGES 1600000
#define F_IN    128
#define F_OUT   32

#define BKT_SHIFT  7
#define BKT_SIZE   128
#define NBKT       782          // ceil(100000/128)
#define BKT_STRIDE 2560         // mean 2046 per bucket, +11 sigma headroom
#define BIN_TILE   8192
#define EPT        32           // edges per thread in bin_kernel
#define NTILES     ((N_EDGES + BIN_TILE - 1) / BIN_TILE)   // 196

typedef _Float16 h2 __attribute__((ext_vector_type(2)));
typedef _Float16 h8 __attribute__((ext_vector_type(8)));

__device__ inline float dot2f(h2 a, h2 b, float c) {
#if __has_builtin(__builtin_amdgcn_fdot2)
    return __builtin_amdgcn_fdot2(a, b, c, false);
#else
    return c + (float)a[0] * (float)b[0] + (float)a[1] * (float)b[1];
#endif
}

__global__ void init_kernel(int* __restrict__ gcur) {
    int i = blockIdx.x * blockDim.x + threadIdx.x;
    if (i < NBKT) gcur[i] = 0;
}

// Bin edges by dst>>7 into 782 buckets; per-(tile,bucket) runs are consecutive
// in the bucket so same-bucket writes share cache lines.
__global__ __launch_bounds__(256) void bin_kernel(const int* __restrict__ ei,
                                                  int* __restrict__ gcur,
                                                  unsigned int* __restrict__ binned) {
    __shared__ int cnt[NBKT], pos[NBKT], gbase[NBKT];
    int t = threadIdx.x;
    for (int b = t; b < NBKT; b += 256) { cnt[b] = 0; pos[b] = 0; }
    __syncthreads();
    int ebase = blockIdx.x * BIN_TILE;
    unsigned int pk[EPT];
    short bkt[EPT];
#pragma unroll
    for (int k = 0; k < EPT; ++k) {
        int e = ebase + k * 256 + t;
        if (e < N_EDGES) {
            int s = ei[e];
            int d = ei[N_EDGES + e];
            bkt[k] = (short)(d >> BKT_SHIFT);
            pk[k]  = (unsigned)s | ((unsigned)(d & (BKT_SIZE - 1)) << 25);
            atomicAdd(&cnt[bkt[k]], 1);
        } else {
            bkt[k] = -1;
        }
    }
    __syncthreads();
    for (int b = t; b < NBKT; b += 256)
        if (cnt[b] > 0) gbase[b] = atomicAdd(&gcur[b], cnt[b]);
    __syncthreads();
#pragma unroll
    for (int k = 0; k < EPT; ++k) {
        if (bkt[k] >= 0) {
            int r = atomicAdd(&pos[bkt[k]], 1);
            int p = gbase[bkt[k]] + r;
            if (p < BKT_STRIDE)
                binned[(size_t)bkt[k] * BKT_STRIDE + p] = pk[k];
        }
    }
}

// Degrees from binned edges: 128-entry LDS int histogram per bucket.
__global__ __launch_bounds__(256) void dinv_from_bins_kernel(const unsigned int* __restrict__ binned,
                                                             const int* __restrict__ gcur,
                                                             float* __restrict__ dinv) {
    __shared__ int cnt[BKT_SIZE];
    int t = threadIdx.x;
    int b = blockIdx.x;
    if (t < BKT_SIZE) cnt[t] = 0;
    __syncthreads();
    int ne = gcur[b];
    if (ne > BKT_STRIDE) ne = BKT_STRIDE;
    const unsigned int* eb = binned + (size_t)b * BKT_STRIDE;
    for (int i = t; i < ne; i += 256)
        atomicAdd(&cnt[eb[i] >> 25], 1);
    __syncthreads();
    int gnode = b * BKT_SIZE + t;
    if (t < BKT_SIZE && gnode < N_NODES)
        dinv[gnode] = rsqrtf((float)(cnt[t] + 1));
}

// hs = fp16( (x @ W) * dinv[row] ), via fp16 LDS tiles + v_dot2_f32_f16.
// 256 rows/block; K chunks of 32 staged as half2 k-pairs, transposed [kk][row].
#define XS_STRIDE 260   // h2 units; 1040 B (16B-aligned), bank spread 2-way
__global__ __launch_bounds__(256) void matmul_kernel(const float4* __restrict__ x4,
                                                     const float4* __restrict__ W4,
                                                     const float* __restrict__ dinv,
                                                     __half* __restrict__ hs) {
    __shared__ h2 xs2[16 * XS_STRIDE];   // 16.6 KB
    __shared__ h2 Ws2[64 * 32];          // 8 KB: [kk][col], kk = k/2
    int t = threadIdx.x;

    // stage W as half2 k-pairs: thread covers kk = t>>2, cols (t&3)*8..+7
    {
        int kk = t >> 2, cq = t & 3;
        float4 a0 = W4[(2 * kk) * 8 + cq * 2];
        float4 a1 = W4[(2 * kk) * 8 + cq * 2 + 1];
        float4 b0 = W4[(2 * kk + 1) * 8 + cq * 2];
        float4 b1 = W4[(2 * kk + 1) * 8 + cq * 2 + 1];
        h8 w0, w1;
        w0[0] = (_Float16)a0.x; w0[1] = (_Float16)b0.x;
        w0[2] = (_Float16)a0.y; w0[3] = (_Float16)b0.y;
        w0[4] = (_Float16)a0.z; w0[5] = (_Float16)b0.z;
        w0[6] = (_Float16)a0.w; w0[7] = (_Float16)b0.w;
        w1[0] = (_Float16)a1.x; w1[1] = (_Float16)b1.x;
        w1[2] = (_Float16)a1.y; w1[3] = (_Float16)b1.y;
        w1[4] = (_Float16)a1.z; w1[5] = (_Float16)b1.z;
        w1[6] = (_Float16)a1.w; w1[7] = (_Float16)b1.w;
        *(h8*)&Ws2[kk * 32 + cq * 8]     = w0;
        *(h8*)&Ws2[kk * 32 + cq * 8 + 4] = w1;
    }

    int rbase = blockIdx.x * 256;
    int rt = t >> 3, ct = t & 7;         // compute: rows rt*8..+7, cols ct*4..+3
    int q = t & 7, rr = t >> 3;          // staging: f4 index q, row rr + it*32
    float acc[32];
#pragma unroll
    for (int i = 0; i < 32; ++i) acc[i] = 0.0f;

    for (int kc = 0; kc < 4; ++kc) {
        __syncthreads();                 // prev chunk consumed (and W staged)
#pragma unroll
        for (int it = 0; it < 8; ++it) {
            int row = it * 32 + rr;
            int grow = rbase + row;
            float4 v = (grow < N_NODES) ? x4[(size_t)grow * 32 + kc * 8 + q]
                                        : make_float4(0, 0, 0, 0);
            h2 hA, hB;
            hA[0] = (_Float16)v.x; hA[1] = (_Float16)v.y;
            hB[0] = (_Float16)v.z; hB[1] = (_Float16)v.w;
            xs2[(q * 2)     * XS_STRIDE + row] = hA;
            xs2[(q * 2 + 1) * XS_STRIDE + row] = hB;
        }
        __syncthreads();
        for (int kk = 0; kk < 16; ++kk) {
            h8 xa0 = *(const h8*)&xs2[kk * XS_STRIDE + rt * 8];
            h8 xa1 = *(const h8*)&xs2[kk * XS_STRIDE + rt * 8 + 4];
            h8 wv  = *(const h8*)&Ws2[(kc * 16 + kk) * 32 + ct * 4];
#pragma unroll
            for (int j = 0; j < 4; ++j) {
                h2 wj; wj[0] = wv[2 * j]; wj[1] = wv[2 * j + 1];
#pragma unroll
                for (int i = 0; i < 4; ++i) {
                    h2 a0; a0[0] = xa0[2 * i]; a0[1] = xa0[2 * i + 1];
                    h2 a1; a1[0] = xa1[2 * i]; a1[1] = xa1[2 * i + 1];
                    acc[i * 4 + j]       = dot2f(a0, wj, acc[i * 4 + j]);
                    acc[(i + 4) * 4 + j] = dot2f(a1, wj, acc[(i + 4) * 4 + j]);
                }
            }
        }
    }
#pragma unroll
    for (int i = 0; i < 8; ++i) {
        int grow = rbase + rt * 8 + i;
        if (grow < N_NODES) {
            float dv = dinv[grow];
            __half2 p0 = __floats2half2_rn(acc[i * 4] * dv, acc[i * 4 + 1] * dv);
            __half2 p1 = __floats2half2_rn(acc[i * 4 + 2] * dv, acc[i * 4 + 3] * dv);
            __half2* dst = (__half2*)&hs[(size_t)grow * F_OUT + ct * 4];
            dst[0] = p0;
            dst[1] = p1;
        }
    }
}

// One block per bucket: in-LDS counting sort by dst_local (int atomics only),
// then per-node register accumulation: 16 lanes per node, half2 gathers.
__global__ __launch_bounds__(256) void aggregate_kernel(const unsigned int* __restrict__ binned,
                                                        const int* __restrict__ gcur,
                                                        const __half2* __restrict__ hs2,
                                                        const float* __restrict__ dinv,
                                                        const float* __restrict__ bias,
                                                        float* __restrict__ out) {
    __shared__ int scan[BKT_SIZE];
    __shared__ int rp[BKT_SIZE + 1];
    __shared__ int cur[BKT_SIZE];
    __shared__ int se[BKT_STRIDE];       // sorted src ids, 10 KB
    int t = threadIdx.x;
    int b = blockIdx.x;
    int ne = gcur[b];
    if (ne > BKT_STRIDE) ne = BKT_STRIDE;
    const unsigned int* eb = binned + (size_t)b * BKT_STRIDE;

    if (t < BKT_SIZE) scan[t] = 0;
    __syncthreads();
    for (int i = t; i < ne; i += 256)
        atomicAdd(&scan[eb[i] >> 25], 1);
    __syncthreads();
    int v = (t < BKT_SIZE) ? scan[t] : 0;
    for (int off = 1; off < BKT_SIZE; off <<= 1) {
        int add = (t < BKT_SIZE && t >= off) ? scan[t - off] : 0;
        __syncthreads();
        if (t < BKT_SIZE) scan[t] += add;
        __syncthreads();
    }
    if (t < BKT_SIZE) {
        int ex = scan[t] - v;            // exclusive prefix
        rp[t] = ex;
        cur[t] = ex;
    }
    if (t == 0) rp[BKT_SIZE] = ne;
    __syncthreads();
    for (int i = t; i < ne; i += 256) {
        unsigned pk = eb[i];
        int dl = (int)(pk >> 25);
        int r = atomicAdd(&cur[dl], 1);
        se[r] = (int)(pk & 0x1FFFFFF);
    }
    __syncthreads();

    int g = t >> 4, j2 = t & 15;         // 16 node-groups x 16 lanes (2 cols/lane)
    for (int n = g; n < BKT_SIZE; n += 16) {
        int gnode = b * BKT_SIZE + n;
        if (gnode >= N_NODES) break;
        int beg = rp[n], end = rp[n + 1];
        float ax = 0.0f, ay = 0.0f;
        int p = beg;
        for (; p + 7 < end; p += 8) {    // 8 independent 4B gathers in flight
            float2 f0 = __half22float2(hs2[(size_t)se[p]     * 16 + j2]);
            float2 f1 = __half22float2(hs2[(size_t)se[p + 1] * 16 + j2]);
            float2 f2 = __half22float2(hs2[(size_t)se[p + 2] * 16 + j2]);
            float2 f3 = __half22float2(hs2[(size_t)se[p + 3] * 16 + j2]);
            float2 f4 = __half22float2(hs2[(size_t)se[p + 4] * 16 + j2]);
            float2 f5 = __half22float2(hs2[(size_t)se[p + 5] * 16 + j2]);
            float2 f6 = __half22float2(hs2[(size_t)se[p + 6] * 16 + j2]);
            float2 f7 = __half22float2(hs2[(size_t)se[p + 7] * 16 + j2]);
            ax += ((f0.x + f1.x) + (f2.x + f3.x)) + ((f4.x + f5.x) + (f6.x + f7.x));
            ay += ((f0.y + f1.y) + (f2.y + f3.y)) + ((f4.y + f5.y) + (f6.y + f7.y));
        }
        for (; p + 3 < end; p += 4) {
            float2 f0 = __half22float2(hs2[(size_t)se[p]     * 16 + j2]);
            float2 f1 = __half22float2(hs2[(size_t)se[p + 1] * 16 + j2]);
            float2 f2 = __half22float2(hs2[(size_t)se[p + 2] * 16 + j2]);
            float2 f3 = __half22float2(hs2[(size_t)se[p + 3] * 16 + j2]);
            ax += (f0.x + f1.x) + (f2.x + f3.x);
            ay += (f0.y + f1.y) + (f2.y + f3.y);
        }
        for (; p < end; ++p) {
            float2 f0 = __half22float2(hs2[(size_t)se[p] * 16 + j2]);
            ax += f0.x;
            ay += f0.y;
        }
        float dv = dinv[gnode];
        float2 sf = __half22float2(hs2[(size_t)gnode * 16 + j2]);
        float2 o;
        o.x = bias[2 * j2]     + dv * (ax + sf.x);
        o.y = bias[2 * j2 + 1] + dv * (ay + sf.y);
        *(float2*)&out[(size_t)gnode * F_OUT + 2 * j2] = o;
    }
}

extern "C" void kernel_launch(void* const* d_in, const int* in_sizes, int n_in,
                              void* d_out, int out_size, void* d_ws, size_t ws_size,
                              hipStream_t stream) {
    const float* x  = (const float*)d_in[0];
    const int*   ei = (const int*)d_in[1];   // int32 on device
    const float* W  = (const float*)d_in[2];
    const float* b  = (const float*)d_in[3];
    float* out = (float*)d_out;

    int*          gcur   = (int*)d_ws;                       // pad to 1024
    unsigned int* binned = (unsigned int*)(gcur + 1024);     // NBKT*BKT_STRIDE ~8 MB
    float*        dinv   = (float*)(binned + (size_t)NBKT * BKT_STRIDE);  // 100000
    __half*       hs     = (__half*)(dinv + ((N_NODES + 3) & ~3));        // 6.4 MB

    const int B = 256;
    const int gN = (N_NODES + B - 1) / B;   // 391

    init_kernel<<<1, 1024, 0, stream>>>(gcur);

    bin_kernel<<<NTILES, B, 0, stream>>>(ei, gcur, binned);

    dinv_from_bins_kernel<<<NBKT, B, 0, stream>>>(binned, gcur, dinv);

    matmul_kernel<<<gN, B, 0, stream>>>((const float4*)x, (const float4*)W, dinv, hs);

    aggregate_kernel<<<NBKT, B, 0, stream>>>(binned, gcur, (const __half2*)hs, dinv, b, out);
}

// Round 9
// 76.775 us; speedup vs baseline: 6.0810x; 1.2028x over previous
//
#include <hip/hip_runtime.h>
#include <hip/hip_fp16.h>

#define N_NODES 100000
#define N_EDGES 1600000
#define F_IN    128
#define F_OUT   32

#define BKT_SHIFT  7
#define BKT_SIZE   128
#define NBKT       782          // ceil(100000/128)
#define BKT_STRIDE 2560         // mean 2046 per bucket, +11 sigma headroom
#define BIN_TILE   4096
#define EPT        16           // edges per thread in bin_kernel
#define NTILES     ((N_EDGES + BIN_TILE - 1) / BIN_TILE)   // 391

typedef _Float16 f16x8 __attribute__((ext_vector_type(8)));
typedef float    f32x4 __attribute__((ext_vector_type(4)));

__global__ void init_kernel(int* __restrict__ gcur) {
    int i = blockIdx.x * blockDim.x + threadIdx.x;
    if (i < NBKT) gcur[i] = 0;
}

// Bin edges by dst>>7 into 782 buckets; per-(tile,bucket) runs are consecutive
// in the bucket so same-bucket writes share cache lines.
__global__ __launch_bounds__(256) void bin_kernel(const int* __restrict__ ei,
                                                  int* __restrict__ gcur,
                                                  unsigned int* __restrict__ binned) {
    __shared__ int cnt[NBKT], pos[NBKT], gbase[NBKT];
    int t = threadIdx.x;
    for (int b = t; b < NBKT; b += 256) { cnt[b] = 0; pos[b] = 0; }
    __syncthreads();
    int ebase = blockIdx.x * BIN_TILE;
    unsigned int pk[EPT];
    short bkt[EPT];
#pragma unroll
    for (int k = 0; k < EPT; ++k) {
        int e = ebase + k * 256 + t;
        if (e < N_EDGES) {
            int s = ei[e];
            int d = ei[N_EDGES + e];
            bkt[k] = (short)(d >> BKT_SHIFT);
            pk[k]  = (unsigned)s | ((unsigned)(d & (BKT_SIZE - 1)) << 25);
            atomicAdd(&cnt[bkt[k]], 1);
        } else {
            bkt[k] = -1;
        }
    }
    __syncthreads();
    for (int b = t; b < NBKT; b += 256)
        if (cnt[b] > 0) gbase[b] = atomicAdd(&gcur[b], cnt[b]);
    __syncthreads();
#pragma unroll
    for (int k = 0; k < EPT; ++k) {
        if (bkt[k] >= 0) {
            int r = atomicAdd(&pos[bkt[k]], 1);
            int p = gbase[bkt[k]] + r;
            if (p < BKT_STRIDE)
                binned[(size_t)bkt[k] * BKT_STRIDE + p] = pk[k];
        }
    }
}

// Degrees from binned edges: 128-entry LDS int histogram per bucket.
__global__ __launch_bounds__(256) void dinv_from_bins_kernel(const unsigned int* __restrict__ binned,
                                                             const int* __restrict__ gcur,
                                                             float* __restrict__ dinv) {
    __shared__ int cnt[BKT_SIZE];
    int t = threadIdx.x;
    int b = blockIdx.x;
    if (t < BKT_SIZE) cnt[t] = 0;
    __syncthreads();
    int ne = gcur[b];
    if (ne > BKT_STRIDE) ne = BKT_STRIDE;
    const unsigned int* eb = binned + (size_t)b * BKT_STRIDE;
    for (int i = t; i < ne; i += 256)
        atomicAdd(&cnt[eb[i] >> 25], 1);
    __syncthreads();
    int gnode = b * BKT_SIZE + t;
    if (t < BKT_SIZE && gnode < N_NODES)
        dinv[gnode] = rsqrtf((float)(cnt[t] + 1));
}

// hs = fp16( (x @ W) * dinv[row] ) via v_mfma_f32_16x16x32_f16.
// 4 waves/block, 16 rows/wave (64 rows/block, grid=1563). A-frags load
// straight from global (coalesced 128B segments); W transposed in LDS.
#define WH_STRIDE 136   // halfs per W column (272 B = 17*16 -> conflict-free b128)
__global__ __launch_bounds__(256) void matmul_kernel(const float4* __restrict__ x4,
                                                     const float* __restrict__ W,
                                                     const float* __restrict__ dinv,
                                                     __half* __restrict__ hs) {
    __shared__ _Float16 Wh[F_OUT * WH_STRIDE];   // 8.7 KB, [col][k]
    int t = threadIdx.x;
    {
        int col = t & 31, kb = (t >> 5) * 16;
        for (int u = 0; u < 16; ++u)
            Wh[col * WH_STRIDE + kb + u] = (_Float16)W[(kb + u) * F_OUT + col];
    }
    __syncthreads();

    int w = t >> 6, l = t & 63;
    int lr = l & 15, kg = l >> 4;                // A row lane, k-group
    int row = blockIdx.x * 64 + w * 16 + lr;
    const float4* xr = x4 + (size_t)row * 32;
    bool rok = row < N_NODES;

    f16x8 a[4];
#pragma unroll
    for (int ks = 0; ks < 4; ++ks) {
        float4 v0, v1;
        if (rok) {
            v0 = xr[ks * 8 + kg * 2];
            v1 = xr[ks * 8 + kg * 2 + 1];
        } else {
            v0 = make_float4(0, 0, 0, 0);
            v1 = v0;
        }
        f16x8 av;
        av[0] = (_Float16)v0.x; av[1] = (_Float16)v0.y;
        av[2] = (_Float16)v0.z; av[3] = (_Float16)v0.w;
        av[4] = (_Float16)v1.x; av[5] = (_Float16)v1.y;
        av[6] = (_Float16)v1.z; av[7] = (_Float16)v1.w;
        a[ks] = av;
    }

    f32x4 c0 = {0.f, 0.f, 0.f, 0.f}, c1 = {0.f, 0.f, 0.f, 0.f};
#pragma unroll
    for (int ks = 0; ks < 4; ++ks) {
        f16x8 b0 = *(const f16x8*)&Wh[lr * WH_STRIDE + ks * 32 + kg * 8];
        f16x8 b1 = *(const f16x8*)&Wh[(16 + lr) * WH_STRIDE + ks * 32 + kg * 8];
        c0 = __builtin_amdgcn_mfma_f32_16x16x32_f16(a[ks], b0, c0, 0, 0, 0);
        c1 = __builtin_amdgcn_mfma_f32_16x16x32_f16(a[ks], b1, c1, 0, 0, 0);
    }

    // D layout: col = lane&15, row = (lane>>4)*4 + i   [m89-verified]
    int orow0 = blockIdx.x * 64 + w * 16 + kg * 4;
#pragma unroll
    for (int i = 0; i < 4; ++i) {
        int orow = orow0 + i;
        if (orow < N_NODES) {
            float dv = dinv[orow];
            hs[(size_t)orow * F_OUT + lr]      = (__half)(c0[i] * dv);
            hs[(size_t)orow * F_OUT + 16 + lr] = (__half)(c1[i] * dv);
        }
    }
}

__device__ inline void acc4(uint2 u, float& a0, float& a1, float& a2, float& a3) {
    float2 f0 = __half22float2(*(__half2*)&u.x);
    float2 f1 = __half22float2(*(__half2*)&u.y);
    a0 += f0.x; a1 += f0.y; a2 += f1.x; a3 += f1.y;
}

// One block per bucket: in-LDS counting sort by dst_local (int atomics only),
// then per-node register accumulation: 8 lanes/node, 8B half4 gathers, 8-deep.
__global__ __launch_bounds__(256) void aggregate_kernel(const unsigned int* __restrict__ binned,
                                                        const int* __restrict__ gcur,
                                                        const uint2* __restrict__ hs4,
                                                        const float* __restrict__ dinv,
                                                        const float* __restrict__ bias,
                                                        float* __restrict__ out) {
    __shared__ int scan[BKT_SIZE];
    __shared__ int rp[BKT_SIZE + 1];
    __shared__ int cur[BKT_SIZE];
    __shared__ int se[BKT_STRIDE];       // sorted src ids, 10 KB
    int t = threadIdx.x;
    int b = blockIdx.x;
    int ne = gcur[b];
    if (ne > BKT_STRIDE) ne = BKT_STRIDE;
    const unsigned int* eb = binned + (size_t)b * BKT_STRIDE;

    if (t < BKT_SIZE) scan[t] = 0;
    __syncthreads();
    for (int i = t; i < ne; i += 256)
        atomicAdd(&scan[eb[i] >> 25], 1);
    __syncthreads();
    int v = (t < BKT_SIZE) ? scan[t] : 0;
    for (int off = 1; off < BKT_SIZE; off <<= 1) {
        int add = (t < BKT_SIZE && t >= off) ? scan[t - off] : 0;
        __syncthreads();
        if (t < BKT_SIZE) scan[t] += add;
        __syncthreads();
    }
    if (t < BKT_SIZE) {
        int ex = scan[t] - v;            // exclusive prefix
        rp[t] = ex;
        cur[t] = ex;
    }
    if (t == 0) rp[BKT_SIZE] = ne;
    __syncthreads();
    for (int i = t; i < ne; i += 256) {
        unsigned pk = eb[i];
        int dl = (int)(pk >> 25);
        int r = atomicAdd(&cur[dl], 1);
        se[r] = (int)(pk & 0x1FFFFFF);
    }
    __syncthreads();

    int slot = t >> 3, j4 = t & 7;       // 32 node-slots x 8 lanes (4 cols/lane)
    float4 bv = *(const float4*)&bias[j4 * 4];
    for (int n = slot; n < BKT_SIZE; n += 32) {
        int gnode = b * BKT_SIZE + n;
        if (gnode >= N_NODES) break;
        int beg = rp[n], end = rp[n + 1];
        float a0 = 0.f, a1 = 0.f, a2 = 0.f, a3 = 0.f;
        int p = beg;
        for (; p + 7 < end; p += 8) {    // 8 independent 8B gathers in flight
            uint2 u0 = hs4[(size_t)se[p]     * 8 + j4];
            uint2 u1 = hs4[(size_t)se[p + 1] * 8 + j4];
            uint2 u2 = hs4[(size_t)se[p + 2] * 8 + j4];
            uint2 u3 = hs4[(size_t)se[p + 3] * 8 + j4];
            uint2 u4 = hs4[(size_t)se[p + 4] * 8 + j4];
            uint2 u5 = hs4[(size_t)se[p + 5] * 8 + j4];
            uint2 u6 = hs4[(size_t)se[p + 6] * 8 + j4];
            uint2 u7 = hs4[(size_t)se[p + 7] * 8 + j4];
            acc4(u0, a0, a1, a2, a3); acc4(u1, a0, a1, a2, a3);
            acc4(u2, a0, a1, a2, a3); acc4(u3, a0, a1, a2, a3);
            acc4(u4, a0, a1, a2, a3); acc4(u5, a0, a1, a2, a3);
            acc4(u6, a0, a1, a2, a3); acc4(u7, a0, a1, a2, a3);
        }
        for (; p + 3 < end; p += 4) {
            uint2 u0 = hs4[(size_t)se[p]     * 8 + j4];
            uint2 u1 = hs4[(size_t)se[p + 1] * 8 + j4];
            uint2 u2 = hs4[(size_t)se[p + 2] * 8 + j4];
            uint2 u3 = hs4[(size_t)se[p + 3] * 8 + j4];
            acc4(u0, a0, a1, a2, a3); acc4(u1, a0, a1, a2, a3);
            acc4(u2, a0, a1, a2, a3); acc4(u3, a0, a1, a2, a3);
        }
        for (; p < end; ++p) {
            uint2 u0 = hs4[(size_t)se[p] * 8 + j4];
            acc4(u0, a0, a1, a2, a3);
        }
        float dv = dinv[gnode];
        uint2 us = hs4[(size_t)gnode * 8 + j4];
        float2 s0 = __half22float2(*(__half2*)&us.x);
        float2 s1 = __half22float2(*(__half2*)&us.y);
        float4 o;
        o.x = bv.x + dv * (a0 + s0.x);
        o.y = bv.y + dv * (a1 + s0.y);
        o.z = bv.z + dv * (a2 + s1.x);
        o.w = bv.w + dv * (a3 + s1.y);
        *(float4*)&out[(size_t)gnode * F_OUT + j4 * 4] = o;
    }
}

extern "C" void kernel_launch(void* const* d_in, const int* in_sizes, int n_in,
                              void* d_out, int out_size, void* d_ws, size_t ws_size,
                              hipStream_t stream) {
    const float* x  = (const float*)d_in[0];
    const int*   ei = (const int*)d_in[1];   // int32 on device
    const float* W  = (const float*)d_in[2];
    const float* b  = (const float*)d_in[3];
    float* out = (float*)d_out;

    int*          gcur   = (int*)d_ws;                       // pad to 1024
    unsigned int* binned = (unsigned int*)(gcur + 1024);     // NBKT*BKT_STRIDE ~8 MB
    float*        dinv   = (float*)(binned + (size_t)NBKT * BKT_STRIDE);  // 100000
    __half*       hs     = (__half*)(dinv + ((N_NODES + 3) & ~3));        // 6.4 MB

    const int B = 256;

    init_kernel<<<1, 1024, 0, stream>>>(gcur);

    bin_kernel<<<NTILES, B, 0, stream>>>(ei, gcur, binned);

    dinv_from_bins_kernel<<<NBKT, B, 0, stream>>>(binned, gcur, dinv);

    matmul_kernel<<<(N_NODES + 63) / 64, B, 0, stream>>>((const float4*)x, W, dinv, hs);

    aggregate_kernel<<<NBKT, B, 0, stream>>>(binned, gcur, (const uint2*)hs, dinv, b, out);
}

// Round 10
// 75.135 us; speedup vs baseline: 6.2137x; 1.0218x over previous
//
#include <hip/hip_runtime.h>
#include <hip/hip_fp16.h>

#define N_NODES 100000
#define N_EDGES 1600000
#define F_IN    128
#define F_OUT   32

#define BKT_SHIFT  7
#define BKT_SIZE   128
#define NBKT       782          // ceil(100000/128)
#define BKT_STRIDE 2560         // mean 2046 per bucket, +11 sigma headroom
#define BIN_TILE   4096
#define EPT        16           // edges per thread in bin_kernel
#define NTILES     ((N_EDGES + BIN_TILE - 1) / BIN_TILE)   // 391

#define AGG_SPLIT  4
#define SUB        32           // nodes per aggregate block
#define SUB_STRIDE 768          // mean 512/sub-bucket, +11 sigma headroom

typedef _Float16 f16x8 __attribute__((ext_vector_type(8)));
typedef float    f32x4 __attribute__((ext_vector_type(4)));

__global__ void init_kernel(int* __restrict__ gcur) {
    int i = blockIdx.x * blockDim.x + threadIdx.x;
    if (i < NBKT) gcur[i] = 0;
}

// Bin edges by dst>>7 into 782 buckets; per-(tile,bucket) runs are consecutive
// in the bucket so same-bucket writes share cache lines.
__global__ __launch_bounds__(256) void bin_kernel(const int* __restrict__ ei,
                                                  int* __restrict__ gcur,
                                                  unsigned int* __restrict__ binned) {
    __shared__ int cnt[NBKT], pos[NBKT], gbase[NBKT];
    int t = threadIdx.x;
    for (int b = t; b < NBKT; b += 256) { cnt[b] = 0; pos[b] = 0; }
    __syncthreads();
    int ebase = blockIdx.x * BIN_TILE;
    unsigned int pk[EPT];
    short bkt[EPT];
#pragma unroll
    for (int k = 0; k < EPT; ++k) {
        int e = ebase + k * 256 + t;
        if (e < N_EDGES) {
            int s = ei[e];
            int d = ei[N_EDGES + e];
            bkt[k] = (short)(d >> BKT_SHIFT);
            pk[k]  = (unsigned)s | ((unsigned)(d & (BKT_SIZE - 1)) << 25);
            atomicAdd(&cnt[bkt[k]], 1);
        } else {
            bkt[k] = -1;
        }
    }
    __syncthreads();
    for (int b = t; b < NBKT; b += 256)
        if (cnt[b] > 0) gbase[b] = atomicAdd(&gcur[b], cnt[b]);
    __syncthreads();
#pragma unroll
    for (int k = 0; k < EPT; ++k) {
        if (bkt[k] >= 0) {
            int r = atomicAdd(&pos[bkt[k]], 1);
            int p = gbase[bkt[k]] + r;
            if (p < BKT_STRIDE)
                binned[(size_t)bkt[k] * BKT_STRIDE + p] = pk[k];
        }
    }
}

// Degrees from binned edges: 128-entry LDS int histogram per bucket.
__global__ __launch_bounds__(256) void dinv_from_bins_kernel(const unsigned int* __restrict__ binned,
                                                             const int* __restrict__ gcur,
                                                             float* __restrict__ dinv) {
    __shared__ int cnt[BKT_SIZE];
    int t = threadIdx.x;
    int b = blockIdx.x;
    if (t < BKT_SIZE) cnt[t] = 0;
    __syncthreads();
    int ne = gcur[b];
    if (ne > BKT_STRIDE) ne = BKT_STRIDE;
    const unsigned int* eb = binned + (size_t)b * BKT_STRIDE;
    for (int i = t; i < ne; i += 256)
        atomicAdd(&cnt[eb[i] >> 25], 1);
    __syncthreads();
    int gnode = b * BKT_SIZE + t;
    if (t < BKT_SIZE && gnode < N_NODES)
        dinv[gnode] = rsqrtf((float)(cnt[t] + 1));
}

// hs = fp16( (x @ W) * dinv[row] ) via v_mfma_f32_16x16x32_f16.
// 4 waves/block, 16 rows/wave (64 rows/block, grid=1563). A-frags load
// straight from global (coalesced 128B segments); W transposed in LDS.
#define WH_STRIDE 136   // halfs per W column (272 B = 17*16 -> conflict-free b128)
__global__ __launch_bounds__(256) void matmul_kernel(const float4* __restrict__ x4,
                                                     const float* __restrict__ W,
                                                     const float* __restrict__ dinv,
                                                     __half* __restrict__ hs) {
    __shared__ _Float16 Wh[F_OUT * WH_STRIDE];   // 8.7 KB, [col][k]
    int t = threadIdx.x;
    {
        int col = t & 31, kb = (t >> 5) * 16;
        for (int u = 0; u < 16; ++u)
            Wh[col * WH_STRIDE + kb + u] = (_Float16)W[(kb + u) * F_OUT + col];
    }
    __syncthreads();

    int w = t >> 6, l = t & 63;
    int lr = l & 15, kg = l >> 4;                // A row lane, k-group
    int row = blockIdx.x * 64 + w * 16 + lr;
    const float4* xr = x4 + (size_t)row * 32;
    bool rok = row < N_NODES;

    f16x8 a[4];
#pragma unroll
    for (int ks = 0; ks < 4; ++ks) {
        float4 v0, v1;
        if (rok) {
            v0 = xr[ks * 8 + kg * 2];
            v1 = xr[ks * 8 + kg * 2 + 1];
        } else {
            v0 = make_float4(0, 0, 0, 0);
            v1 = v0;
        }
        f16x8 av;
        av[0] = (_Float16)v0.x; av[1] = (_Float16)v0.y;
        av[2] = (_Float16)v0.z; av[3] = (_Float16)v0.w;
        av[4] = (_Float16)v1.x; av[5] = (_Float16)v1.y;
        av[6] = (_Float16)v1.z; av[7] = (_Float16)v1.w;
        a[ks] = av;
    }

    f32x4 c0 = {0.f, 0.f, 0.f, 0.f}, c1 = {0.f, 0.f, 0.f, 0.f};
#pragma unroll
    for (int ks = 0; ks < 4; ++ks) {
        f16x8 b0 = *(const f16x8*)&Wh[lr * WH_STRIDE + ks * 32 + kg * 8];
        f16x8 b1 = *(const f16x8*)&Wh[(16 + lr) * WH_STRIDE + ks * 32 + kg * 8];
        c0 = __builtin_amdgcn_mfma_f32_16x16x32_f16(a[ks], b0, c0, 0, 0, 0);
        c1 = __builtin_amdgcn_mfma_f32_16x16x32_f16(a[ks], b1, c1, 0, 0, 0);
    }

    // D layout: col = lane&15, row = (lane>>4)*4 + i   [m89-verified]
    int orow0 = blockIdx.x * 64 + w * 16 + kg * 4;
#pragma unroll
    for (int i = 0; i < 4; ++i) {
        int orow = orow0 + i;
        if (orow < N_NODES) {
            float dv = dinv[orow];
            hs[(size_t)orow * F_OUT + lr]      = (__half)(c0[i] * dv);
            hs[(size_t)orow * F_OUT + 16 + lr] = (__half)(c1[i] * dv);
        }
    }
}

__device__ inline void acc4(uint2 u, float& a0, float& a1, float& a2, float& a3) {
    float2 f0 = __half22float2(*(__half2*)&u.x);
    float2 f1 = __half22float2(*(__half2*)&u.y);
    a0 += f0.x; a1 += f0.y; a2 += f1.x; a3 += f1.y;
}

// 4 blocks per bucket, 32 nodes each (grid 3128 -> ~12 blocks/CU).
// Single eb read into registers, filter own quarter, LDS counting sort,
// then 8 lanes/node x 8B half4 gathers, 8-deep unrolled.
__global__ __launch_bounds__(256) void aggregate_kernel(const unsigned int* __restrict__ binned,
                                                        const int* __restrict__ gcur,
                                                        const uint2* __restrict__ hs4,
                                                        const float* __restrict__ dinv,
                                                        const float* __restrict__ bias,
                                                        float* __restrict__ out) {
    __shared__ int scan[SUB];
    __shared__ int rp[SUB + 1];
    __shared__ int cur[SUB];
    __shared__ int se[SUB_STRIDE];       // 3 KB
    int t = threadIdx.x;
    int b   = blockIdx.x >> 2;           // bucket
    int sub = blockIdx.x & 3;            // quarter of the bucket
    int ne = gcur[b];
    if (ne > BKT_STRIDE) ne = BKT_STRIDE;
    const unsigned int* eb = binned + (size_t)b * BKT_STRIDE;

    if (t < SUB) scan[t] = 0;
    __syncthreads();

    unsigned pk[10];
#pragma unroll
    for (int k = 0; k < 10; ++k) {
        int i = t + k * 256;
        pk[k] = (i < ne) ? eb[i] : 0xFFFFFFFFu;
    }
#pragma unroll
    for (int k = 0; k < 10; ++k) {
        if (pk[k] != 0xFFFFFFFFu) {
            int dl = (int)(pk[k] >> 25);
            if ((dl >> 5) == sub) atomicAdd(&scan[dl & 31], 1);
        }
    }
    __syncthreads();
    int v = (t < SUB) ? scan[t] : 0;
    for (int off = 1; off < SUB; off <<= 1) {
        int add = (t < SUB && t >= off) ? scan[t - off] : 0;
        __syncthreads();
        if (t < SUB) scan[t] += add;
        __syncthreads();
    }
    if (t < SUB) {
        int ex = scan[t] - v;            // exclusive prefix
        if (ex > SUB_STRIDE) ex = SUB_STRIDE;
        rp[t] = ex;
        cur[t] = ex;
    }
    if (t == 0) rp[SUB] = (scan[SUB - 1] < SUB_STRIDE) ? 0 : SUB_STRIDE;  // fixed below
    __syncthreads();
    if (t == 0) {
        int tot = scan[SUB - 1];
        rp[SUB] = (tot > SUB_STRIDE) ? SUB_STRIDE : tot;
    }
    __syncthreads();
#pragma unroll
    for (int k = 0; k < 10; ++k) {
        if (pk[k] != 0xFFFFFFFFu) {
            int dl = (int)(pk[k] >> 25);
            if ((dl >> 5) == sub) {
                int r = atomicAdd(&cur[dl & 31], 1);
                if (r < SUB_STRIDE) se[r] = (int)(pk[k] & 0x1FFFFFF);
            }
        }
    }
    __syncthreads();

    int n = t >> 3, j4 = t & 7;          // 32 nodes x 8 lanes (4 cols/lane)
    int gnode = b * BKT_SIZE + sub * SUB + n;
    if (gnode >= N_NODES) return;
    float4 bv = *(const float4*)&bias[j4 * 4];
    int beg = rp[n], end = rp[n + 1];
    float a0 = 0.f, a1 = 0.f, a2 = 0.f, a3 = 0.f;
    int p = beg;
    for (; p + 7 < end; p += 8) {        // 8 independent 8B gathers in flight
        uint2 u0 = hs4[(size_t)se[p]     * 8 + j4];
        uint2 u1 = hs4[(size_t)se[p + 1] * 8 + j4];
        uint2 u2 = hs4[(size_t)se[p + 2] * 8 + j4];
        uint2 u3 = hs4[(size_t)se[p + 3] * 8 + j4];
        uint2 u4 = hs4[(size_t)se[p + 4] * 8 + j4];
        uint2 u5 = hs4[(size_t)se[p + 5] * 8 + j4];
        uint2 u6 = hs4[(size_t)se[p + 6] * 8 + j4];
        uint2 u7 = hs4[(size_t)se[p + 7] * 8 + j4];
        acc4(u0, a0, a1, a2, a3); acc4(u1, a0, a1, a2, a3);
        acc4(u2, a0, a1, a2, a3); acc4(u3, a0, a1, a2, a3);
        acc4(u4, a0, a1, a2, a3); acc4(u5, a0, a1, a2, a3);
        acc4(u6, a0, a1, a2, a3); acc4(u7, a0, a1, a2, a3);
    }
    for (; p + 3 < end; p += 4) {
        uint2 u0 = hs4[(size_t)se[p]     * 8 + j4];
        uint2 u1 = hs4[(size_t)se[p + 1] * 8 + j4];
        uint2 u2 = hs4[(size_t)se[p + 2] * 8 + j4];
        uint2 u3 = hs4[(size_t)se[p + 3] * 8 + j4];
        acc4(u0, a0, a1, a2, a3); acc4(u1, a0, a1, a2, a3);
        acc4(u2, a0, a1, a2, a3); acc4(u3, a0, a1, a2, a3);
    }
    for (; p < end; ++p) {
        uint2 u0 = hs4[(size_t)se[p] * 8 + j4];
        acc4(u0, a0, a1, a2, a3);
    }
    float dv = dinv[gnode];
    uint2 us = hs4[(size_t)gnode * 8 + j4];
    float2 s0 = __half22float2(*(__half2*)&us.x);
    float2 s1 = __half22float2(*(__half2*)&us.y);
    float4 o;
    o.x = bv.x + dv * (a0 + s0.x);
    o.y = bv.y + dv * (a1 + s0.y);
    o.z = bv.z + dv * (a2 + s1.x);
    o.w = bv.w + dv * (a3 + s1.y);
    *(float4*)&out[(size_t)gnode * F_OUT + j4 * 4] = o;
}

extern "C" void kernel_launch(void* const* d_in, const int* in_sizes, int n_in,
                              void* d_out, int out_size, void* d_ws, size_t ws_size,
                              hipStream_t stream) {
    const float* x  = (const float*)d_in[0];
    const int*   ei = (const int*)d_in[1];   // int32 on device
    const float* W  = (const float*)d_in[2];
    const float* b  = (const float*)d_in[3];
    float* out = (float*)d_out;

    int*          gcur   = (int*)d_ws;                       // pad to 1024
    unsigned int* binned = (unsigned int*)(gcur + 1024);     // NBKT*BKT_STRIDE ~8 MB
    float*        dinv   = (float*)(binned + (size_t)NBKT * BKT_STRIDE);  // 100000
    __half*       hs     = (__half*)(dinv + ((N_NODES + 3) & ~3));        // 6.4 MB

    const int B = 256;

    init_kernel<<<1, 1024, 0, stream>>>(gcur);

    bin_kernel<<<NTILES, B, 0, stream>>>(ei, gcur, binned);

    dinv_from_bins_kernel<<<NBKT, B, 0, stream>>>(binned, gcur, dinv);

    matmul_kernel<<<(N_NODES + 63) / 64, B, 0, stream>>>((const float4*)x, W, dinv, hs);

    aggregate_kernel<<<NBKT * AGG_SPLIT, B, 0, stream>>>(binned, gcur, (const uint2*)hs, dinv, b, out);
}

// Round 11
// 68.080 us; speedup vs baseline: 6.8576x; 1.1036x over previous
//
#include <hip/hip_runtime.h>
#include <hip/hip_fp16.h>

#define N_NODES 100000
#define N_EDGES 1600000
#define F_IN    128
#define F_OUT   32

#define BKT_SHIFT  7
#define BKT_SIZE   128
#define NBKT       782          // ceil(100000/128)
#define BKT_STRIDE 2560         // mean 2046 per bucket, +11 sigma headroom

#define BIN_THREADS 512
#define BIN_TILE    8192
#define EPT         (BIN_TILE / BIN_THREADS)               // 16
#define NTILES      ((N_EDGES + BIN_TILE - 1) / BIN_TILE)  // 196

#define AGG_SPLIT  4
#define SUB        32           // nodes per aggregate block
#define SUB_STRIDE 768          // mean 512/sub-bucket, +11 sigma headroom

typedef _Float16 f16x8 __attribute__((ext_vector_type(8)));
typedef float    f32x4 __attribute__((ext_vector_type(4)));

__global__ void init_kernel(int* __restrict__ gcur) {
    int i = blockIdx.x * blockDim.x + threadIdx.x;
    if (i < NBKT) gcur[i] = 0;
}

// Bin edges by dst>>7 into 782 buckets. Rank-capture: one LDS atomic per edge
// gives both the histogram and the in-tile rank; 8192-edge tiles make
// same-bucket runs ~10 edges -> mostly full-line global writes.
__global__ __launch_bounds__(BIN_THREADS) void bin_kernel(const int* __restrict__ ei,
                                                          int* __restrict__ gcur,
                                                          unsigned int* __restrict__ binned) {
    __shared__ int cnt[NBKT], gbase[NBKT];
    int t = threadIdx.x;
    for (int b = t; b < NBKT; b += BIN_THREADS) cnt[b] = 0;
    __syncthreads();
    int ebase = blockIdx.x * BIN_TILE;
    unsigned int pk[EPT];
    int rk[EPT];
    short bkt[EPT];
#pragma unroll
    for (int k = 0; k < EPT; ++k) {
        int e = ebase + k * BIN_THREADS + t;
        if (e < N_EDGES) {
            int s = ei[e];
            int d = ei[N_EDGES + e];
            bkt[k] = (short)(d >> BKT_SHIFT);
            pk[k]  = (unsigned)s | ((unsigned)(d & (BKT_SIZE - 1)) << 25);
            rk[k]  = atomicAdd(&cnt[bkt[k]], 1);
        } else {
            bkt[k] = -1;
        }
    }
    __syncthreads();
    for (int b = t; b < NBKT; b += BIN_THREADS)
        if (cnt[b] > 0) gbase[b] = atomicAdd(&gcur[b], cnt[b]);
    __syncthreads();
#pragma unroll
    for (int k = 0; k < EPT; ++k) {
        if (bkt[k] >= 0) {
            int p = gbase[bkt[k]] + rk[k];
            if (p < BKT_STRIDE)
                binned[(size_t)bkt[k] * BKT_STRIDE + p] = pk[k];
        }
    }
}

// Fused: per-bucket degree histogram (-> dinv in LDS) + MFMA matmul for the
// bucket's 128 rows. hs = fp16( (x @ W) * dinv[row] ).
// 512 threads = 8 waves of 16 rows; A-frags straight from global (coalesced);
// W transposed once into LDS.
#define WH_STRIDE 136   // halfs per W column (272 B -> conflict-free b128)
__global__ __launch_bounds__(512) void matmul_kernel(const float4* __restrict__ x4,
                                                     const float* __restrict__ W,
                                                     const unsigned int* __restrict__ binned,
                                                     const int* __restrict__ gcur,
                                                     __half* __restrict__ hs) {
    __shared__ _Float16 Wh[F_OUT * WH_STRIDE];   // 8.7 KB, [col][k]
    __shared__ int cnt128[BKT_SIZE];
    __shared__ float dinvL[BKT_SIZE];
    int t = threadIdx.x;
    int b = blockIdx.x;

    if (t < BKT_SIZE) cnt128[t] = 0;
    {
        int col = t & 31, kb = (t >> 5) * 8;
        for (int u = 0; u < 8; ++u)
            Wh[col * WH_STRIDE + kb + u] = (_Float16)W[(kb + u) * F_OUT + col];
    }
    __syncthreads();

    int ne = gcur[b];
    if (ne > BKT_STRIDE) ne = BKT_STRIDE;
    const unsigned int* eb = binned + (size_t)b * BKT_STRIDE;
    for (int i = t; i < ne; i += 512)
        atomicAdd(&cnt128[eb[i] >> 25], 1);
    __syncthreads();
    if (t < BKT_SIZE) dinvL[t] = rsqrtf((float)(cnt128[t] + 1));  // +1 self loop
    __syncthreads();

    int w = t >> 6, l = t & 63;
    int lr = l & 15, kg = l >> 4;                // A row lane, k-group
    int row = b * 128 + w * 16 + lr;
    const float4* xr = x4 + (size_t)row * 32;
    bool rok = row < N_NODES;

    f16x8 a[4];
#pragma unroll
    for (int ks = 0; ks < 4; ++ks) {
        float4 v0, v1;
        if (rok) {
            v0 = xr[ks * 8 + kg * 2];
            v1 = xr[ks * 8 + kg * 2 + 1];
        } else {
            v0 = make_float4(0, 0, 0, 0);
            v1 = v0;
        }
        f16x8 av;
        av[0] = (_Float16)v0.x; av[1] = (_Float16)v0.y;
        av[2] = (_Float16)v0.z; av[3] = (_Float16)v0.w;
        av[4] = (_Float16)v1.x; av[5] = (_Float16)v1.y;
        av[6] = (_Float16)v1.z; av[7] = (_Float16)v1.w;
        a[ks] = av;
    }

    f32x4 c0 = {0.f, 0.f, 0.f, 0.f}, c1 = {0.f, 0.f, 0.f, 0.f};
#pragma unroll
    for (int ks = 0; ks < 4; ++ks) {
        f16x8 b0 = *(const f16x8*)&Wh[lr * WH_STRIDE + ks * 32 + kg * 8];
        f16x8 b1 = *(const f16x8*)&Wh[(16 + lr) * WH_STRIDE + ks * 32 + kg * 8];
        c0 = __builtin_amdgcn_mfma_f32_16x16x32_f16(a[ks], b0, c0, 0, 0, 0);
        c1 = __builtin_amdgcn_mfma_f32_16x16x32_f16(a[ks], b1, c1, 0, 0, 0);
    }

    // D layout: col = lane&15, row = (lane>>4)*4 + i   [m89-verified]
    int lrow0 = w * 16 + kg * 4;
#pragma unroll
    for (int i = 0; i < 4; ++i) {
        int orow = b * 128 + lrow0 + i;
        if (orow < N_NODES) {
            float dv = dinvL[lrow0 + i];
            hs[(size_t)orow * F_OUT + lr]      = (__half)(c0[i] * dv);
            hs[(size_t)orow * F_OUT + 16 + lr] = (__half)(c1[i] * dv);
        }
    }
}

__device__ inline void acc4(uint2 u, float& a0, float& a1, float& a2, float& a3) {
    float2 f0 = __half22float2(*(__half2*)&u.x);
    float2 f1 = __half22float2(*(__half2*)&u.y);
    a0 += f0.x; a1 += f0.y; a2 += f1.x; a3 += f1.y;
}

// 4 blocks per bucket, 32 nodes each (grid 3128). Rank-capture counting sort
// of the sub-bucket's edges, dinv[dst] derived from the local degree count,
// then 8 lanes/node x 8B half4 gathers, 8-deep unrolled.
__global__ __launch_bounds__(256) void aggregate_kernel(const unsigned int* __restrict__ binned,
                                                        const int* __restrict__ gcur,
                                                        const uint2* __restrict__ hs4,
                                                        const float* __restrict__ bias,
                                                        float* __restrict__ out) {
    __shared__ int cnt[SUB];
    __shared__ int sc[SUB];
    __shared__ int rp[SUB + 1];
    __shared__ int se[SUB_STRIDE];       // 3 KB
    int t = threadIdx.x;
    int b   = blockIdx.x >> 2;           // bucket
    int sub = blockIdx.x & 3;            // quarter of the bucket
    int ne = gcur[b];
    if (ne > BKT_STRIDE) ne = BKT_STRIDE;
    const unsigned int* eb = binned + (size_t)b * BKT_STRIDE;

    if (t < SUB) cnt[t] = 0;
    __syncthreads();

    unsigned pk[10];
    int rk[10];
#pragma unroll
    for (int k = 0; k < 10; ++k) {
        int i = t + k * 256;
        pk[k] = (i < ne) ? eb[i] : 0xFFFFFFFFu;
    }
#pragma unroll
    for (int k = 0; k < 10; ++k) {
        rk[k] = -1;
        if (pk[k] != 0xFFFFFFFFu) {
            int dl = (int)(pk[k] >> 25);
            if ((dl >> 5) == sub) rk[k] = atomicAdd(&cnt[dl & 31], 1);
        }
    }
    __syncthreads();
    int v = (t < SUB) ? cnt[t] : 0;
    if (t < SUB) sc[t] = v;
    __syncthreads();
    for (int off = 1; off < SUB; off <<= 1) {
        int add = (t < SUB && t >= off) ? sc[t - off] : 0;
        __syncthreads();
        if (t < SUB) sc[t] += add;
        __syncthreads();
    }
    if (t < SUB) {
        int ex = sc[t] - v;              // exclusive prefix
        rp[t] = (ex < SUB_STRIDE) ? ex : SUB_STRIDE;
    }
    if (t == 0) rp[SUB] = 0;             // placeholder
    __syncthreads();
    if (t == 0) {
        int tot = sc[SUB - 1];
        rp[SUB] = (tot > SUB_STRIDE) ? SUB_STRIDE : tot;
    }
    __syncthreads();
#pragma unroll
    for (int k = 0; k < 10; ++k) {
        if (rk[k] >= 0) {
            int dl = (int)(pk[k] >> 25);
            int pos = rp[dl & 31] + rk[k];
            if (pos < SUB_STRIDE) se[pos] = (int)(pk[k] & 0x1FFFFFF);
        }
    }
    __syncthreads();

    int n = t >> 3, j4 = t & 7;          // 32 nodes x 8 lanes (4 cols/lane)
    int gnode = b * BKT_SIZE + sub * SUB + n;
    if (gnode >= N_NODES) return;
    float4 bv = *(const float4*)&bias[j4 * 4];
    int deg = cnt[n];
    int beg = rp[n];
    int end = rp[n + 1];
    if (beg + deg < end) end = beg + deg;
    float a0 = 0.f, a1 = 0.f, a2 = 0.f, a3 = 0.f;
    int p = beg;
    for (; p + 7 < end; p += 8) {        // 8 independent 8B gathers in flight
        uint2 u0 = hs4[(size_t)se[p]     * 8 + j4];
        uint2 u1 = hs4[(size_t)se[p + 1] * 8 + j4];
        uint2 u2 = hs4[(size_t)se[p + 2] * 8 + j4];
        uint2 u3 = hs4[(size_t)se[p + 3] * 8 + j4];
        uint2 u4 = hs4[(size_t)se[p + 4] * 8 + j4];
        uint2 u5 = hs4[(size_t)se[p + 5] * 8 + j4];
        uint2 u6 = hs4[(size_t)se[p + 6] * 8 + j4];
        uint2 u7 = hs4[(size_t)se[p + 7] * 8 + j4];
        acc4(u0, a0, a1, a2, a3); acc4(u1, a0, a1, a2, a3);
        acc4(u2, a0, a1, a2, a3); acc4(u3, a0, a1, a2, a3);
        acc4(u4, a0, a1, a2, a3); acc4(u5, a0, a1, a2, a3);
        acc4(u6, a0, a1, a2, a3); acc4(u7, a0, a1, a2, a3);
    }
    for (; p + 3 < end; p += 4) {
        uint2 u0 = hs4[(size_t)se[p]     * 8 + j4];
        uint2 u1 = hs4[(size_t)se[p + 1] * 8 + j4];
        uint2 u2 = hs4[(size_t)se[p + 2] * 8 + j4];
        uint2 u3 = hs4[(size_t)se[p + 3] * 8 + j4];
        acc4(u0, a0, a1, a2, a3); acc4(u1, a0, a1, a2, a3);
        acc4(u2, a0, a1, a2, a3); acc4(u3, a0, a1, a2, a3);
    }
    for (; p < end; ++p) {
        uint2 u0 = hs4[(size_t)se[p] * 8 + j4];
        acc4(u0, a0, a1, a2, a3);
    }
    float dv = rsqrtf((float)(deg + 1));   // same value matmul folded for src
    uint2 us = hs4[(size_t)gnode * 8 + j4];
    float2 s0 = __half22float2(*(__half2*)&us.x);
    float2 s1 = __half22float2(*(__half2*)&us.y);
    float4 o;
    o.x = bv.x + dv * (a0 + s0.x);
    o.y = bv.y + dv * (a1 + s0.y);
    o.z = bv.z + dv * (a2 + s1.x);
    o.w = bv.w + dv * (a3 + s1.y);
    *(float4*)&out[(size_t)gnode * F_OUT + j4 * 4] = o;
}

extern "C" void kernel_launch(void* const* d_in, const int* in_sizes, int n_in,
                              void* d_out, int out_size, void* d_ws, size_t ws_size,
                              hipStream_t stream) {
    const float* x  = (const float*)d_in[0];
    const int*   ei = (const int*)d_in[1];   // int32 on device
    const float* W  = (const float*)d_in[2];
    const float* b  = (const float*)d_in[3];
    float* out = (float*)d_out;

    int*          gcur   = (int*)d_ws;                       // pad to 1024
    unsigned int* binned = (unsigned int*)(gcur + 1024);     // NBKT*BKT_STRIDE ~8 MB
    __half*       hs     = (__half*)(binned + (size_t)NBKT * BKT_STRIDE);  // 6.4 MB

    init_kernel<<<1, 1024, 0, stream>>>(gcur);

    bin_kernel<<<NTILES, BIN_THREADS, 0, stream>>>(ei, gcur, binned);

    matmul_kernel<<<NBKT, 512, 0, stream>>>((const float4*)x, W, binned, gcur, hs);

    aggregate_kernel<<<NBKT * AGG_SPLIT, 256, 0, stream>>>(binned, gcur, (const uint2*)hs, b, out);
}